// Round 1
// baseline (123.126 us; speedup 1.0000x reference)
//
#include <hip/hip_runtime.h>
#include <hip/hip_bf16.h>
#include <math.h>

#define LOG2E 1.4426950408889634f

// ---------------------------------------------------------------------------
// Kernel 1: per-atom precompute of (Zf, Z^|a_exp|) into workspace as float2.
// ---------------------------------------------------------------------------
__global__ void zbl_precompute_za(const int* __restrict__ Z,
                                  const float* __restrict__ a_exp,
                                  float2* __restrict__ zfza, int n) {
    int i = blockIdx.x * blockDim.x + threadIdx.x;
    if (i < n) {
        float zf = (float)Z[i];
        float za = powf(zf, fabsf(a_exp[0]));
        zfza[i] = make_float2(zf, za);
    }
}

// ---------------------------------------------------------------------------
// Kernel 2: per-pair ZBL + wave-level segmented reduction (idx_i is sorted).
// ---------------------------------------------------------------------------
__global__ void __launch_bounds__(256)
zbl_pairs(const float* __restrict__ dist, const float* __restrict__ cut,
          const int* __restrict__ idx_i, const int* __restrict__ idx_j,
          const float2* __restrict__ zfza,
          const float* __restrict__ a_coef,
          const float* __restrict__ phi_c, const float* __restrict__ phi_e,
          const float* __restrict__ ke, const float* __restrict__ d2a,
          const float* __restrict__ e2m,
          float* __restrict__ out, int n) {
    // Uniform params (compiler scalarizes: all addresses wave-uniform).
    float inv_ac = __fdividef(1.0f, fabsf(a_coef[0]));
    float c0 = fabsf(phi_c[0]), c1 = fabsf(phi_c[1]),
          c2 = fabsf(phi_c[2]), c3 = fabsf(phi_c[3]);
    float cnorm = __fdividef(1.0f, c0 + c1 + c2 + c3);
    c0 *= cnorm; c1 *= cnorm; c2 *= cnorm; c3 *= cnorm;
    // exp(-e*x) = exp2(-(e*log2e)*x)
    float e0 = fabsf(phi_e[0]) * LOG2E, e1 = fabsf(phi_e[1]) * LOG2E,
          e2 = fabsf(phi_e[2]) * LOG2E, e3 = fabsf(phi_e[3]) * LOG2E;
    float scale = ke[0] * e2m[0];
    float d2a0  = d2a[0];

    int p = blockIdx.x * blockDim.x + threadIdx.x;

    int   ii  = -1;
    float val = 0.0f;
    if (p < n) {
        ii = idx_i[p];
        int jj = idx_j[p];
        float2 zi = zfza[ii];   // sorted -> broadcast-ish within wave
        float2 zj = zfza[jj];   // random gather, 800 KB table lives in L2
        float d   = dist[p];
        float arg = d * (zi.y + zj.y) * inv_ac;
        float phi = c0 * exp2f(-e0 * arg) + c1 * exp2f(-e1 * arg)
                  + c2 * exp2f(-e2 * arg) + c3 * exp2f(-e3 * arg);
        val = scale * zi.x * zj.x * phi * cut[p];
        val = __fdividef(val, d * d2a0);
    }

    // Wave-64 segmented inclusive scan over (ii, val); idx_i sorted so equal
    // indices are contiguous. 6 shuffle rounds.
    int lane = threadIdx.x & 63;
    #pragma unroll
    for (int off = 1; off < 64; off <<= 1) {
        float ov = __shfl_up(val, (unsigned)off, 64);
        int   oi = __shfl_up(ii, (unsigned)off, 64);
        if (lane >= off && oi == ii) val += ov;
    }
    // Tail lane of each segment commits one atomic.
    int nxt = __shfl_down(ii, 1u, 64);
    bool tail = (lane == 63) || (nxt != ii);
    if (p < n && tail) atomicAdd(out + ii, val);
}

// ---------------------------------------------------------------------------
// Fallback (ws too small): compute za on the fly per pair.
// ---------------------------------------------------------------------------
__global__ void __launch_bounds__(256)
zbl_pairs_nows(const float* __restrict__ dist, const float* __restrict__ cut,
               const int* __restrict__ idx_i, const int* __restrict__ idx_j,
               const int* __restrict__ Z,
               const float* __restrict__ a_coef, const float* __restrict__ a_exp,
               const float* __restrict__ phi_c, const float* __restrict__ phi_e,
               const float* __restrict__ ke, const float* __restrict__ d2a,
               const float* __restrict__ e2m,
               float* __restrict__ out, int n) {
    float inv_ac = __fdividef(1.0f, fabsf(a_coef[0]));
    float aexp = fabsf(a_exp[0]);
    float c0 = fabsf(phi_c[0]), c1 = fabsf(phi_c[1]),
          c2 = fabsf(phi_c[2]), c3 = fabsf(phi_c[3]);
    float cnorm = __fdividef(1.0f, c0 + c1 + c2 + c3);
    c0 *= cnorm; c1 *= cnorm; c2 *= cnorm; c3 *= cnorm;
    float e0 = fabsf(phi_e[0]) * LOG2E, e1 = fabsf(phi_e[1]) * LOG2E,
          e2 = fabsf(phi_e[2]) * LOG2E, e3 = fabsf(phi_e[3]) * LOG2E;
    float scale = ke[0] * e2m[0];
    float d2a0  = d2a[0];

    int p = blockIdx.x * blockDim.x + threadIdx.x;
    int   ii  = -1;
    float val = 0.0f;
    if (p < n) {
        ii = idx_i[p];
        int jj = idx_j[p];
        float zif = (float)Z[ii];
        float zjf = (float)Z[jj];
        float zai = exp2f(__log2f(zif) * aexp);   // Z >= 1
        float zaj = exp2f(__log2f(zjf) * aexp);
        float d   = dist[p];
        float arg = d * (zai + zaj) * inv_ac;
        float phi = c0 * exp2f(-e0 * arg) + c1 * exp2f(-e1 * arg)
                  + c2 * exp2f(-e2 * arg) + c3 * exp2f(-e3 * arg);
        val = scale * zif * zjf * phi * cut[p];
        val = __fdividef(val, d * d2a0);
    }

    int lane = threadIdx.x & 63;
    #pragma unroll
    for (int off = 1; off < 64; off <<= 1) {
        float ov = __shfl_up(val, (unsigned)off, 64);
        int   oi = __shfl_up(ii, (unsigned)off, 64);
        if (lane >= off && oi == ii) val += ov;
    }
    int nxt = __shfl_down(ii, 1u, 64);
    bool tail = (lane == 63) || (nxt != ii);
    if (p < n && tail) atomicAdd(out + ii, val);
}

extern "C" void kernel_launch(void* const* d_in, const int* in_sizes, int n_in,
                              void* d_out, int out_size, void* d_ws, size_t ws_size,
                              hipStream_t stream) {
    const int*   atomic_numbers = (const int*)  d_in[0];
    const float* distances      = (const float*)d_in[1];
    const float* cutoffs        = (const float*)d_in[2];
    const int*   idx_i          = (const int*)  d_in[3];
    const int*   idx_j          = (const int*)  d_in[4];
    const float* a_coefficient  = (const float*)d_in[5];
    const float* a_exponent     = (const float*)d_in[6];
    const float* phi_coeffs     = (const float*)d_in[7];
    const float* phi_exps       = (const float*)d_in[8];
    const float* ke             = (const float*)d_in[9];
    const float* d2a            = (const float*)d_in[10];
    const float* e2m            = (const float*)d_in[11];
    float* out = (float*)d_out;

    const int n_atoms = in_sizes[0];
    const int n_pairs = in_sizes[1];

    // Harness poisons d_out with 0xAA before every timed call; we accumulate
    // with atomics, so zero it (memset node is graph-capture safe).
    hipMemsetAsync(d_out, 0, (size_t)out_size * sizeof(float), stream);

    const int block = 256;
    const int grid_pairs = (n_pairs + block - 1) / block;

    size_t need = (size_t)n_atoms * sizeof(float2);
    if (ws_size >= need) {
        float2* zfza = (float2*)d_ws;
        int grid_atoms = (n_atoms + block - 1) / block;
        zbl_precompute_za<<<grid_atoms, block, 0, stream>>>(
            atomic_numbers, a_exponent, zfza, n_atoms);
        zbl_pairs<<<grid_pairs, block, 0, stream>>>(
            distances, cutoffs, idx_i, idx_j, zfza,
            a_coefficient, phi_coeffs, phi_exps, ke, d2a, e2m,
            out, n_pairs);
    } else {
        zbl_pairs_nows<<<grid_pairs, block, 0, stream>>>(
            distances, cutoffs, idx_i, idx_j, atomic_numbers,
            a_coefficient, a_exponent, phi_coeffs, phi_exps, ke, d2a, e2m,
            out, n_pairs);
    }
}